// Round 5
// baseline (315.628 us; speedup 1.0000x reference)
//
#include <hip/hip_runtime.h>

#define DHID 128
#define BCAP 10240         // per-bucket capacity (mean 8163, 23 sigma)
#define PCHUNK 4096        // edges per partition block

typedef _Float16 h4 __attribute__((ext_vector_type(4)));
typedef _Float16 h8 __attribute__((ext_vector_type(8)));

// ---------------- phase 1: partition edges into 512-node buckets ----------------
// packed entry: (dst & 511) << 17 | src   (src < 2^17)
__global__ __launch_bounds__(256) void k_partition(const int* __restrict__ ei, int E, int nbuck,
                                                   int* __restrict__ bucket_cursor,
                                                   unsigned* __restrict__ packed) {
    __shared__ unsigned sdata[PCHUNK];
    __shared__ int lcnt[256], lbase[256], loff[256], lcur[256], sscan[256];
    int t = threadIdx.x;
    int e0 = blockIdx.x * PCHUNK;
    lcnt[t] = 0;
    __syncthreads();

    for (int i = t; i < PCHUNK; i += 256) {
        int e = e0 + i;
        if (e < E) {
            int d = ei[E + e];
            atomicAdd(&lcnt[d >> 9], 1);
        }
    }
    __syncthreads();

    int c = lcnt[t];
    sscan[t] = c;
    __syncthreads();
    for (int off = 1; off < 256; off <<= 1) {
        int v = (t >= off) ? sscan[t - off] : 0;
        __syncthreads();
        sscan[t] += v;
        __syncthreads();
    }
    loff[t] = sscan[t] - c;
    if (t < nbuck && c > 0) lbase[t] = atomicAdd(&bucket_cursor[t], c);
    lcur[t] = sscan[t] - c;
    __syncthreads();

    for (int i = t; i < PCHUNK; i += 256) {
        int e = e0 + i;
        if (e < E) {
            int s = ei[e];
            int d = ei[E + e];
            int b = d >> 9;
            int pos = atomicAdd(&lcur[b], 1);
            sdata[pos] = ((unsigned)(d & 511) << 17) | (unsigned)s;
        }
    }
    __syncthreads();

    int wid = t >> 6, lane = t & 63;
    for (int b = wid; b < nbuck; b += 4) {
        int cb = lcnt[b];
        if (cb == 0) continue;
        int gbase = b * BCAP + lbase[b];
        int sbase = loff[b];
        for (int k = lane; k < cb; k += 64) packed[gbase + k] = sdata[sbase + k];
    }
}

// ---------------- phase 2a: per-node degree ----------------
__global__ __launch_bounds__(256) void k_p2a(const unsigned* __restrict__ packed,
                                             const int* __restrict__ bucket_cursor,
                                             int* __restrict__ cnt, int N) {
    __shared__ int c512[512];
    int t = threadIdx.x, b = blockIdx.x;
    c512[t] = 0; c512[t + 256] = 0;
    __syncthreads();
    int m = bucket_cursor[b];
    const unsigned* pb = packed + (size_t)b * BCAP;
    for (int i = t; i < m; i += 256) atomicAdd(&c512[pb[i] >> 17], 1);
    __syncthreads();
    int base = b << 9;
#pragma unroll
    for (int j = 0; j < 2; ++j) {
        int node = base + t + j * 256;
        if (node < N) cnt[node] = c512[t + j * 256];
    }
}

__global__ void k_dinv(const int* __restrict__ cnt, float* __restrict__ dinv, int N) {
    int i = blockIdx.x * 256 + threadIdx.x;
    if (i < N) dinv[i] = rsqrtf((float)(cnt[i] + 1));
}

__global__ void k_reduce(const int* __restrict__ cnt, int* __restrict__ partial, int N) {
    __shared__ int s[256];
    int t = threadIdx.x;
    int i = blockIdx.x * 256 + t;
    s[t] = (i < N) ? cnt[i] : 0;
    __syncthreads();
    for (int st = 128; st > 0; st >>= 1) {
        if (t < st) s[t] += s[t + st];
        __syncthreads();
    }
    if (t == 0) partial[blockIdx.x] = s[0];
}

__global__ void k_scan_partials(const int* __restrict__ partial, int* __restrict__ blockoff, int NB) {
    __shared__ int s[1024];
    int t = threadIdx.x;
    s[t] = (t < NB) ? partial[t] : 0;
    __syncthreads();
    for (int off = 1; off < 1024; off <<= 1) {
        int v = (t >= off) ? s[t - off] : 0;
        __syncthreads();
        s[t] += v;
        __syncthreads();
    }
    if (t < NB) blockoff[t] = (t == 0) ? 0 : s[t - 1];
}

__global__ void k_scan_block(const int* __restrict__ cnt, const int* __restrict__ blockoff,
                             int* __restrict__ row_ptr, int N, int E) {
    __shared__ int s[256];
    int t = threadIdx.x;
    int i = blockIdx.x * 256 + t;
    int c = (i < N) ? cnt[i] : 0;
    s[t] = c;
    __syncthreads();
    for (int off = 1; off < 256; off <<= 1) {
        int v = (t >= off) ? s[t - off] : 0;
        __syncthreads();
        s[t] += v;
        __syncthreads();
    }
    if (i < N) row_ptr[i] = blockoff[blockIdx.x] + s[t] - c;
    if (i == 0) row_ptr[N] = E;
}

// ---------------- phase 2b: in-bucket counting sort -> csr ----------------
__global__ __launch_bounds__(256) void k_p2b(const unsigned* __restrict__ packed,
                                             const int* __restrict__ bucket_cursor,
                                             const int* __restrict__ row_ptr,
                                             int* __restrict__ csr, int N) {
    __shared__ int c512[512], cur512[512], sscan[256];
    int t = threadIdx.x, b = blockIdx.x;
    c512[t] = 0; c512[t + 256] = 0;
    __syncthreads();
    int m = bucket_cursor[b];
    const unsigned* pb = packed + (size_t)b * BCAP;
    for (int i = t; i < m; i += 256) atomicAdd(&c512[pb[i] >> 17], 1);
    __syncthreads();
    int v0 = c512[2 * t], v1 = c512[2 * t + 1];
    int ps = v0 + v1;
    sscan[t] = ps;
    __syncthreads();
    for (int off = 1; off < 256; off <<= 1) {
        int v = (t >= off) ? sscan[t - off] : 0;
        __syncthreads();
        sscan[t] += v;
        __syncthreads();
    }
    int excl = sscan[t] - ps;
    cur512[2 * t] = excl;
    cur512[2 * t + 1] = excl + v0;
    __syncthreads();
    int rbase = row_ptr[b << 9];
    for (int i = t; i < m; i += 256) {
        unsigned p = pb[i];
        int dl = p >> 17;
        int src = (int)(p & 0x1FFFFu);
        int pos = atomicAdd(&cur512[dl], 1);
        csr[rbase + pos] = src;
    }
}

// ---------------- GEMM: Th[N,128] = fp16( dinv[row] * (X @ W) ) ----------------
// 512 threads = 8 waves; tile 128 rows x 128 cols; thread = 8 rows x 4 cols.
// One ds_read_b128 of W per k serves 8 rows (halves LDS traffic vs 4-row tile).
// TIN = float (layer 1) or _Float16 (layer 2, reads fp16 H).
template <typename TIN>
__global__ __launch_bounds__(512, 4) void k_gemm(const TIN* __restrict__ X,
                                                 const float* __restrict__ W,
                                                 const float* __restrict__ dinv,
                                                 _Float16* __restrict__ Th, int N) {
    __shared__ float Ws[DHID * DHID];
    int t = threadIdx.x;
    {
        const float4* Wg4 = (const float4*)W;
        float4* Ws4 = (float4*)Ws;
#pragma unroll
        for (int i = 0; i < 8; ++i) Ws4[i * 512 + t] = Wg4[i * 512 + t];
    }
    __syncthreads();

    int tr = t >> 5;            // 0..15
    int tc = t & 31;            // 0..31
    int row0 = blockIdx.x * 128 + tr * 8;
    int col  = tc * 4;
    if (row0 >= N) return;      // no barriers below

    int r[8];
#pragma unroll
    for (int j = 0; j < 8; ++j) {
        int rr = row0 + j;
        r[j] = (rr < N) ? rr : (N - 1);   // clamp loads; stores guarded
    }

    float acc[8][4];
#pragma unroll
    for (int j = 0; j < 8; ++j)
#pragma unroll
        for (int c = 0; c < 4; ++c) acc[j][c] = 0.f;

    if constexpr (sizeof(TIN) == 4) {
        // fp32 input: k-step 4, per-row float4 loads
        for (int k4 = 0; k4 < DHID; k4 += 4) {
            float4 a[8];
#pragma unroll
            for (int j = 0; j < 8; ++j)
                a[j] = *(const float4*)((const float*)X + (size_t)r[j] * DHID + k4);
#pragma unroll
            for (int kk = 0; kk < 4; ++kk) {
                float4 w = *(const float4*)&Ws[(k4 + kk) * DHID + col];
#pragma unroll
                for (int j = 0; j < 8; ++j) {
                    float av = (kk == 0) ? a[j].x : (kk == 1) ? a[j].y : (kk == 2) ? a[j].z : a[j].w;
                    acc[j][0] = fmaf(av, w.x, acc[j][0]);
                    acc[j][1] = fmaf(av, w.y, acc[j][1]);
                    acc[j][2] = fmaf(av, w.z, acc[j][2]);
                    acc[j][3] = fmaf(av, w.w, acc[j][3]);
                }
            }
        }
    } else {
        // fp16 input: k-step 8, per-row h8 (16B) loads
        for (int k8 = 0; k8 < DHID; k8 += 8) {
            h8 a[8];
#pragma unroll
            for (int j = 0; j < 8; ++j)
                a[j] = *(const h8*)((const _Float16*)X + (size_t)r[j] * DHID + k8);
#pragma unroll
            for (int kk = 0; kk < 8; ++kk) {
                float4 w = *(const float4*)&Ws[(k8 + kk) * DHID + col];
#pragma unroll
                for (int j = 0; j < 8; ++j) {
                    float av = (float)a[j][kk];
                    acc[j][0] = fmaf(av, w.x, acc[j][0]);
                    acc[j][1] = fmaf(av, w.y, acc[j][1]);
                    acc[j][2] = fmaf(av, w.z, acc[j][2]);
                    acc[j][3] = fmaf(av, w.w, acc[j][3]);
                }
            }
        }
    }

#pragma unroll
    for (int j = 0; j < 8; ++j) {
        int rr = row0 + j;
        if (rr < N) {
            float s = dinv[rr];
            h4 v;
#pragma unroll
            for (int c = 0; c < 4; ++c) v[c] = (_Float16)(acc[j][c] * s);
            *(h4*)(Th + (size_t)rr * DHID + col) = v;
        }
    }
}

// ---------------- aggregation: 4 nodes per wave, 16 lanes x h8 per node --------
// Th rows pre-scaled by dinv[src].  res = relu(dinv[node]*(sum Th[src] + Th[node]) + b)
// FINAL=0: store res as fp16 H.  FINAL=1: fuse res @ Wl + bl (16-lane reduce).
template <int FINAL>
__global__ __launch_bounds__(256) void k_agg(const _Float16* __restrict__ Th,
                                             const int* __restrict__ row_ptr,
                                             const int* __restrict__ csr_src,
                                             const float* __restrict__ dinv,
                                             const float* __restrict__ bias,
                                             void* __restrict__ outp,
                                             const float* __restrict__ Wl,
                                             const float* __restrict__ bl, int N) {
    int node = blockIdx.x * 16 + (threadIdx.x >> 4);
    int sl = threadIdx.x & 15;
    if (node >= N) return;

    int e = row_ptr[node];
    int end = row_ptr[node + 1];
    const h8* Tl = (const h8*)Th + sl;        // row r at Tl[r*16]; 16B per lane

    float acc[8];
#pragma unroll
    for (int c = 0; c < 8; ++c) acc[c] = 0.f;

    // 4-deep gather pipeline
    for (; e + 4 <= end; e += 4) {
        int s0 = csr_src[e];
        int s1 = csr_src[e + 1];
        int s2 = csr_src[e + 2];
        int s3 = csr_src[e + 3];
        h8 v0 = Tl[(size_t)s0 * 16];
        h8 v1 = Tl[(size_t)s1 * 16];
        h8 v2 = Tl[(size_t)s2 * 16];
        h8 v3 = Tl[(size_t)s3 * 16];
#pragma unroll
        for (int c = 0; c < 8; ++c)
            acc[c] += ((float)v0[c] + (float)v1[c]) + ((float)v2[c] + (float)v3[c]);
    }
    for (; e < end; ++e) {
        int s0 = csr_src[e];
        h8 va = Tl[(size_t)s0 * 16];
#pragma unroll
        for (int c = 0; c < 8; ++c) acc[c] += (float)va[c];
    }

    {   // self-loop (Th already dinv-scaled)
        h8 tv = Tl[(size_t)node * 16];
#pragma unroll
        for (int c = 0; c < 8; ++c) acc[c] += (float)tv[c];
    }

    float dn = dinv[node];
    const float* bp = bias + sl * 8;
    float4 b0 = *(const float4*)bp;
    float4 b1 = *(const float4*)(bp + 4);
    float r[8];
    r[0] = fmaxf(fmaf(dn, acc[0], b0.x), 0.f);
    r[1] = fmaxf(fmaf(dn, acc[1], b0.y), 0.f);
    r[2] = fmaxf(fmaf(dn, acc[2], b0.z), 0.f);
    r[3] = fmaxf(fmaf(dn, acc[3], b0.w), 0.f);
    r[4] = fmaxf(fmaf(dn, acc[4], b1.x), 0.f);
    r[5] = fmaxf(fmaf(dn, acc[5], b1.y), 0.f);
    r[6] = fmaxf(fmaf(dn, acc[6], b1.z), 0.f);
    r[7] = fmaxf(fmaf(dn, acc[7], b1.w), 0.f);

    if (FINAL == 0) {
        h8 v;
#pragma unroll
        for (int c = 0; c < 8; ++c) v[c] = (_Float16)r[c];
        *(h8*)((_Float16*)outp + (size_t)node * DHID + sl * 8) = v;
    } else {
        const float* wp = Wl + sl * 8;
        float4 w0 = *(const float4*)wp;
        float4 w1 = *(const float4*)(wp + 4);
        float p = r[0] * w0.x + r[1] * w0.y + r[2] * w0.z + r[3] * w0.w +
                  r[4] * w1.x + r[5] * w1.y + r[6] * w1.z + r[7] * w1.w;
#pragma unroll
        for (int off = 8; off > 0; off >>= 1) p += __shfl_down(p, off, 16);
        if (sl == 0) ((float*)outp)[node] = p + bl[0];
    }
}

// ---------------- launch ----------------
extern "C" void kernel_launch(void* const* d_in, const int* in_sizes, int n_in,
                              void* d_out, int out_size, void* d_ws, size_t ws_size,
                              hipStream_t stream) {
    const float* x  = (const float*)d_in[0];
    const int*   ei = (const int*)d_in[1];
    const float* W1 = (const float*)d_in[2];
    const float* b1 = (const float*)d_in[3];
    const float* W2 = (const float*)d_in[4];
    const float* b2 = (const float*)d_in[5];
    const float* Wl = (const float*)d_in[6];
    const float* bl = (const float*)d_in[7];
    float* out = (float*)d_out;

    int N = in_sizes[0] / DHID;     // 100000
    int E = in_sizes[1] / 2;        // 1600000
    int NB = (N + 255) / 256;       // 391
    int nbuck = (N + 511) / 512;    // 196

    char* ws = (char*)d_ws;
    size_t off = 0;
    auto alloc = [&](size_t bytes) -> void* {
        void* p = ws + off;
        off += (bytes + 255) & ~(size_t)255;
        return p;
    };
    int*      cnt      = (int*)alloc((size_t)N * 4);
    float*    dinv     = (float*)alloc((size_t)N * 4);
    int*      row_ptr  = (int*)alloc((size_t)(N + 1) * 4);
    int*      partial  = (int*)alloc((size_t)NB * 4);
    int*      blockoff = (int*)alloc((size_t)NB * 4);
    int*      bcur     = (int*)alloc((size_t)nbuck * 4);
    int*      csr      = (int*)alloc((size_t)E * 4);
    unsigned* packed   = (unsigned*)alloc((size_t)nbuck * BCAP * 4);
    _Float16* Th       = (_Float16*)alloc((size_t)N * DHID * 2);
    _Float16* H        = (_Float16*)alloc((size_t)N * DHID * 2);

    // ---- CSR build (bucketed counting sort; reused by both layers) ----
    (void)hipMemsetAsync(bcur, 0, (size_t)nbuck * 4, stream);
    k_partition<<<(E + PCHUNK - 1) / PCHUNK, 256, 0, stream>>>(ei, E, nbuck, bcur, packed);
    k_p2a<<<nbuck, 256, 0, stream>>>(packed, bcur, cnt, N);
    k_dinv<<<NB, 256, 0, stream>>>(cnt, dinv, N);
    k_reduce<<<NB, 256, 0, stream>>>(cnt, partial, N);
    k_scan_partials<<<1, 1024, 0, stream>>>(partial, blockoff, NB);
    k_scan_block<<<NB, 256, 0, stream>>>(cnt, blockoff, row_ptr, N, E);
    k_p2b<<<nbuck, 256, 0, stream>>>(packed, bcur, row_ptr, csr, N);

    int gemm_grid = (N + 127) / 128;   // 782

    // ---- layer 1 ----
    k_gemm<float><<<gemm_grid, 512, 0, stream>>>(x, W1, dinv, Th, N);
    k_agg<0><<<(N + 15) / 16, 256, 0, stream>>>(Th, row_ptr, csr, dinv, b1, H, nullptr, nullptr, N);

    // ---- layer 2 + fused final projection ----
    k_gemm<_Float16><<<gemm_grid, 512, 0, stream>>>(H, W2, dinv, Th, N);
    k_agg<1><<<(N + 15) / 16, 256, 0, stream>>>(Th, row_ptr, csr, dinv, b2, out, Wl, bl, N);
}

// Round 6
// 245.330 us; speedup vs baseline: 1.2865x; 1.2865x over previous
//
#include <hip/hip_runtime.h>

#define DHID 128
#define BCAP 10240         // per-bucket capacity (mean 8163, 23 sigma)
#define PCHUNK 4096        // edges per partition block

typedef _Float16 h4 __attribute__((ext_vector_type(4)));
typedef _Float16 h8 __attribute__((ext_vector_type(8)));
typedef _Float16 f16x8 __attribute__((ext_vector_type(8)));
typedef float    f32x4 __attribute__((ext_vector_type(4)));

// ---------------- phase 1: partition edges into 512-node buckets ----------------
// packed entry: (dst & 511) << 17 | src   (src < 2^17)
__global__ __launch_bounds__(256) void k_partition(const int* __restrict__ ei, int E, int nbuck,
                                                   int* __restrict__ bucket_cursor,
                                                   unsigned* __restrict__ packed) {
    __shared__ unsigned sdata[PCHUNK];
    __shared__ int lcnt[256], lbase[256], loff[256], lcur[256], sscan[256];
    int t = threadIdx.x;
    int e0 = blockIdx.x * PCHUNK;
    lcnt[t] = 0;
    __syncthreads();

    for (int i = t; i < PCHUNK; i += 256) {
        int e = e0 + i;
        if (e < E) {
            int d = ei[E + e];
            atomicAdd(&lcnt[d >> 9], 1);
        }
    }
    __syncthreads();

    int c = lcnt[t];
    sscan[t] = c;
    __syncthreads();
    for (int off = 1; off < 256; off <<= 1) {
        int v = (t >= off) ? sscan[t - off] : 0;
        __syncthreads();
        sscan[t] += v;
        __syncthreads();
    }
    loff[t] = sscan[t] - c;
    if (t < nbuck && c > 0) lbase[t] = atomicAdd(&bucket_cursor[t], c);
    lcur[t] = sscan[t] - c;
    __syncthreads();

    for (int i = t; i < PCHUNK; i += 256) {
        int e = e0 + i;
        if (e < E) {
            int s = ei[e];
            int d = ei[E + e];
            int b = d >> 9;
            int pos = atomicAdd(&lcur[b], 1);
            sdata[pos] = ((unsigned)(d & 511) << 17) | (unsigned)s;
        }
    }
    __syncthreads();

    int wid = t >> 6, lane = t & 63;
    for (int b = wid; b < nbuck; b += 4) {
        int cb = lcnt[b];
        if (cb == 0) continue;
        int gbase = b * BCAP + lbase[b];
        int sbase = loff[b];
        for (int k = lane; k < cb; k += 64) packed[gbase + k] = sdata[sbase + k];
    }
}

// ---------------- phase 2a: per-node degree ----------------
__global__ __launch_bounds__(256) void k_p2a(const unsigned* __restrict__ packed,
                                             const int* __restrict__ bucket_cursor,
                                             int* __restrict__ cnt, int N) {
    __shared__ int c512[512];
    int t = threadIdx.x, b = blockIdx.x;
    c512[t] = 0; c512[t + 256] = 0;
    __syncthreads();
    int m = bucket_cursor[b];
    const unsigned* pb = packed + (size_t)b * BCAP;
    for (int i = t; i < m; i += 256) atomicAdd(&c512[pb[i] >> 17], 1);
    __syncthreads();
    int base = b << 9;
#pragma unroll
    for (int j = 0; j < 2; ++j) {
        int node = base + t + j * 256;
        if (node < N) cnt[node] = c512[t + j * 256];
    }
}

__global__ void k_dinv(const int* __restrict__ cnt, float* __restrict__ dinv, int N) {
    int i = blockIdx.x * 256 + threadIdx.x;
    if (i < N) dinv[i] = rsqrtf((float)(cnt[i] + 1));
}

__global__ void k_reduce(const int* __restrict__ cnt, int* __restrict__ partial, int N) {
    __shared__ int s[256];
    int t = threadIdx.x;
    int i = blockIdx.x * 256 + t;
    s[t] = (i < N) ? cnt[i] : 0;
    __syncthreads();
    for (int st = 128; st > 0; st >>= 1) {
        if (t < st) s[t] += s[t + st];
        __syncthreads();
    }
    if (t == 0) partial[blockIdx.x] = s[0];
}

__global__ void k_scan_partials(const int* __restrict__ partial, int* __restrict__ blockoff, int NB) {
    __shared__ int s[1024];
    int t = threadIdx.x;
    s[t] = (t < NB) ? partial[t] : 0;
    __syncthreads();
    for (int off = 1; off < 1024; off <<= 1) {
        int v = (t >= off) ? s[t - off] : 0;
        __syncthreads();
        s[t] += v;
        __syncthreads();
    }
    if (t < NB) blockoff[t] = (t == 0) ? 0 : s[t - 1];
}

__global__ void k_scan_block(const int* __restrict__ cnt, const int* __restrict__ blockoff,
                             int* __restrict__ row_ptr, int N, int E) {
    __shared__ int s[256];
    int t = threadIdx.x;
    int i = blockIdx.x * 256 + t;
    int c = (i < N) ? cnt[i] : 0;
    s[t] = c;
    __syncthreads();
    for (int off = 1; off < 256; off <<= 1) {
        int v = (t >= off) ? s[t - off] : 0;
        __syncthreads();
        s[t] += v;
        __syncthreads();
    }
    if (i < N) row_ptr[i] = blockoff[blockIdx.x] + s[t] - c;
    if (i == 0) row_ptr[N] = E;
}

// ---------------- phase 2b: in-bucket counting sort -> csr ----------------
__global__ __launch_bounds__(256) void k_p2b(const unsigned* __restrict__ packed,
                                             const int* __restrict__ bucket_cursor,
                                             const int* __restrict__ row_ptr,
                                             int* __restrict__ csr, int N) {
    __shared__ int c512[512], cur512[512], sscan[256];
    int t = threadIdx.x, b = blockIdx.x;
    c512[t] = 0; c512[t + 256] = 0;
    __syncthreads();
    int m = bucket_cursor[b];
    const unsigned* pb = packed + (size_t)b * BCAP;
    for (int i = t; i < m; i += 256) atomicAdd(&c512[pb[i] >> 17], 1);
    __syncthreads();
    int v0 = c512[2 * t], v1 = c512[2 * t + 1];
    int ps = v0 + v1;
    sscan[t] = ps;
    __syncthreads();
    for (int off = 1; off < 256; off <<= 1) {
        int v = (t >= off) ? sscan[t - off] : 0;
        __syncthreads();
        sscan[t] += v;
        __syncthreads();
    }
    int excl = sscan[t] - ps;
    cur512[2 * t] = excl;
    cur512[2 * t + 1] = excl + v0;
    __syncthreads();
    int rbase = row_ptr[b << 9];
    for (int i = t; i < m; i += 256) {
        unsigned p = pb[i];
        int dl = p >> 17;
        int src = (int)(p & 0x1FFFFu);
        int pos = atomicAdd(&cur512[dl], 1);
        csr[rbase + pos] = src;
    }
}

// ---------------- MFMA GEMM: Th[N,128] = fp16( dinv[r] * (X @ W) ) ----------------
// v_mfma_f32_16x16x32_f16 with SWAPPED operands: A := W^T (hoisted to registers,
// loop-invariant), B := X^T. D = W^T X^T = (XW)^T, whose C-layout gives each lane
// one row r and 4 consecutive cols -> contiguous 8B fp16 stores.
// Block = 256 thr = 4 waves; wave w owns cols [w*32, w*32+32); grid-strides 32-row blocks.
// Frag maps (16x16x32): A: lane -> A[l&15][(l>>4)*8+j]; B: B[(l>>4)*8+j][l&15];
// D: row=(l>>4)*4+reg, col=l&15.   [guide §3, m89-verified]
template <typename TIN>
__global__ __launch_bounds__(256) void k_gemm_mfma(const TIN* __restrict__ X,
                                                   const float* __restrict__ W,
                                                   const float* __restrict__ dinv,
                                                   _Float16* __restrict__ Th,
                                                   int N, int nRB) {
    int t = threadIdx.x;
    int w = t >> 6;          // wave 0..3
    int l = t & 63;
    int l16 = l & 15;
    int lq = l >> 4;         // 0..3

    // Hoist A-frags = W^T: afrag[ct][kb], element j = W[(kb*32+lq*8+j)][w*32+ct*16+l16]
    f16x8 afrag[2][4];
#pragma unroll
    for (int ct = 0; ct < 2; ++ct) {
        int c = w * 32 + ct * 16 + l16;
#pragma unroll
        for (int kb = 0; kb < 4; ++kb) {
            f16x8 a;
#pragma unroll
            for (int j = 0; j < 8; ++j)
                a[j] = (_Float16)W[(kb * 32 + lq * 8 + j) * DHID + c];
            afrag[ct][kb] = a;
        }
    }

    for (int rb = blockIdx.x; rb < nRB; rb += gridDim.x) {
        int r0 = rb * 32;
        f16x8 bfrag[2][4];
#pragma unroll
        for (int rt = 0; rt < 2; ++rt) {
            int r = r0 + rt * 16 + l16;
            int rc = (r < N) ? r : N - 1;       // clamp loads; stores guarded
            const TIN* xp = X + (size_t)rc * DHID + lq * 8;
#pragma unroll
            for (int kb = 0; kb < 4; ++kb) {
                if constexpr (sizeof(TIN) == 4) {
                    float4 x0 = *(const float4*)((const float*)xp + kb * 32);
                    float4 x1 = *(const float4*)((const float*)xp + kb * 32 + 4);
                    f16x8 b;
                    b[0] = (_Float16)x0.x; b[1] = (_Float16)x0.y;
                    b[2] = (_Float16)x0.z; b[3] = (_Float16)x0.w;
                    b[4] = (_Float16)x1.x; b[5] = (_Float16)x1.y;
                    b[6] = (_Float16)x1.z; b[7] = (_Float16)x1.w;
                    bfrag[rt][kb] = b;
                } else {
                    bfrag[rt][kb] = *(const f16x8*)((const _Float16*)xp + kb * 32);
                }
            }
        }

        f32x4 acc[2][2];
#pragma unroll
        for (int rt = 0; rt < 2; ++rt)
#pragma unroll
            for (int ct = 0; ct < 2; ++ct) {
                f32x4 d = {0.f, 0.f, 0.f, 0.f};
#pragma unroll
                for (int kb = 0; kb < 4; ++kb)
                    d = __builtin_amdgcn_mfma_f32_16x16x32_f16(afrag[ct][kb], bfrag[rt][kb], d, 0, 0, 0);
                acc[rt][ct] = d;
            }

#pragma unroll
        for (int rt = 0; rt < 2; ++rt) {
            int r = r0 + rt * 16 + l16;
            if (r < N) {
                float s = dinv[r];
#pragma unroll
                for (int ct = 0; ct < 2; ++ct) {
                    h4 v;
#pragma unroll
                    for (int j = 0; j < 4; ++j) v[j] = (_Float16)(acc[rt][ct][j] * s);
                    *(h4*)(Th + (size_t)r * DHID + w * 32 + ct * 16 + lq * 4) = v;
                }
            }
        }
    }
}

// ---------------- aggregation: 4 nodes per wave, 16 lanes x h8 per node --------
// Th rows pre-scaled by dinv[src].  res = relu(dinv[node]*(sum Th[src] + Th[node]) + b)
// FINAL=0: store res as fp16 H.  FINAL=1: fuse res @ Wl + bl (16-lane reduce).
template <int FINAL>
__global__ __launch_bounds__(256) void k_agg(const _Float16* __restrict__ Th,
                                             const int* __restrict__ row_ptr,
                                             const int* __restrict__ csr_src,
                                             const float* __restrict__ dinv,
                                             const float* __restrict__ bias,
                                             void* __restrict__ outp,
                                             const float* __restrict__ Wl,
                                             const float* __restrict__ bl, int N) {
    int node = blockIdx.x * 16 + (threadIdx.x >> 4);
    int sl = threadIdx.x & 15;
    if (node >= N) return;

    int e = row_ptr[node];
    int end = row_ptr[node + 1];
    const h8* Tl = (const h8*)Th + sl;        // row r at Tl[r*16]; 16B per lane

    float acc[8];
#pragma unroll
    for (int c = 0; c < 8; ++c) acc[c] = 0.f;

    for (; e + 4 <= end; e += 4) {
        int s0 = csr_src[e];
        int s1 = csr_src[e + 1];
        int s2 = csr_src[e + 2];
        int s3 = csr_src[e + 3];
        h8 v0 = Tl[(size_t)s0 * 16];
        h8 v1 = Tl[(size_t)s1 * 16];
        h8 v2 = Tl[(size_t)s2 * 16];
        h8 v3 = Tl[(size_t)s3 * 16];
#pragma unroll
        for (int c = 0; c < 8; ++c)
            acc[c] += ((float)v0[c] + (float)v1[c]) + ((float)v2[c] + (float)v3[c]);
    }
    for (; e < end; ++e) {
        int s0 = csr_src[e];
        h8 va = Tl[(size_t)s0 * 16];
#pragma unroll
        for (int c = 0; c < 8; ++c) acc[c] += (float)va[c];
    }

    {   // self-loop (Th already dinv-scaled)
        h8 tv = Tl[(size_t)node * 16];
#pragma unroll
        for (int c = 0; c < 8; ++c) acc[c] += (float)tv[c];
    }

    float dn = dinv[node];
    const float* bp = bias + sl * 8;
    float4 b0 = *(const float4*)bp;
    float4 b1 = *(const float4*)(bp + 4);
    float r[8];
    r[0] = fmaxf(fmaf(dn, acc[0], b0.x), 0.f);
    r[1] = fmaxf(fmaf(dn, acc[1], b0.y), 0.f);
    r[2] = fmaxf(fmaf(dn, acc[2], b0.z), 0.f);
    r[3] = fmaxf(fmaf(dn, acc[3], b0.w), 0.f);
    r[4] = fmaxf(fmaf(dn, acc[4], b1.x), 0.f);
    r[5] = fmaxf(fmaf(dn, acc[5], b1.y), 0.f);
    r[6] = fmaxf(fmaf(dn, acc[6], b1.z), 0.f);
    r[7] = fmaxf(fmaf(dn, acc[7], b1.w), 0.f);

    if (FINAL == 0) {
        h8 v;
#pragma unroll
        for (int c = 0; c < 8; ++c) v[c] = (_Float16)r[c];
        *(h8*)((_Float16*)outp + (size_t)node * DHID + sl * 8) = v;
    } else {
        const float* wp = Wl + sl * 8;
        float4 w0 = *(const float4*)wp;
        float4 w1 = *(const float4*)(wp + 4);
        float p = r[0] * w0.x + r[1] * w0.y + r[2] * w0.z + r[3] * w0.w +
                  r[4] * w1.x + r[5] * w1.y + r[6] * w1.z + r[7] * w1.w;
#pragma unroll
        for (int off = 8; off > 0; off >>= 1) p += __shfl_down(p, off, 16);
        if (sl == 0) ((float*)outp)[node] = p + bl[0];
    }
}

// ---------------- launch ----------------
extern "C" void kernel_launch(void* const* d_in, const int* in_sizes, int n_in,
                              void* d_out, int out_size, void* d_ws, size_t ws_size,
                              hipStream_t stream) {
    const float* x  = (const float*)d_in[0];
    const int*   ei = (const int*)d_in[1];
    const float* W1 = (const float*)d_in[2];
    const float* b1 = (const float*)d_in[3];
    const float* W2 = (const float*)d_in[4];
    const float* b2 = (const float*)d_in[5];
    const float* Wl = (const float*)d_in[6];
    const float* bl = (const float*)d_in[7];
    float* out = (float*)d_out;

    int N = in_sizes[0] / DHID;     // 100000
    int E = in_sizes[1] / 2;        // 1600000
    int NB = (N + 255) / 256;       // 391
    int nbuck = (N + 511) / 512;    // 196
    int nRB = (N + 31) / 32;        // 3125

    char* ws = (char*)d_ws;
    size_t off = 0;
    auto alloc = [&](size_t bytes) -> void* {
        void* p = ws + off;
        off += (bytes + 255) & ~(size_t)255;
        return p;
    };
    int*      cnt      = (int*)alloc((size_t)N * 4);
    float*    dinv     = (float*)alloc((size_t)N * 4);
    int*      row_ptr  = (int*)alloc((size_t)(N + 1) * 4);
    int*      partial  = (int*)alloc((size_t)NB * 4);
    int*      blockoff = (int*)alloc((size_t)NB * 4);
    int*      bcur     = (int*)alloc((size_t)nbuck * 4);
    int*      csr      = (int*)alloc((size_t)E * 4);
    unsigned* packed   = (unsigned*)alloc((size_t)nbuck * BCAP * 4);
    _Float16* Th       = (_Float16*)alloc((size_t)N * DHID * 2);
    _Float16* H        = (_Float16*)alloc((size_t)N * DHID * 2);

    // ---- CSR build (bucketed counting sort; reused by both layers) ----
    (void)hipMemsetAsync(bcur, 0, (size_t)nbuck * 4, stream);
    k_partition<<<(E + PCHUNK - 1) / PCHUNK, 256, 0, stream>>>(ei, E, nbuck, bcur, packed);
    k_p2a<<<nbuck, 256, 0, stream>>>(packed, bcur, cnt, N);
    k_dinv<<<NB, 256, 0, stream>>>(cnt, dinv, N);
    k_reduce<<<NB, 256, 0, stream>>>(cnt, partial, N);
    k_scan_partials<<<1, 1024, 0, stream>>>(partial, blockoff, NB);
    k_scan_block<<<NB, 256, 0, stream>>>(cnt, blockoff, row_ptr, N, E);
    k_p2b<<<nbuck, 256, 0, stream>>>(packed, bcur, row_ptr, csr, N);

    // ---- layer 1 ----
    k_gemm_mfma<float><<<1024, 256, 0, stream>>>(x, W1, dinv, Th, N, nRB);
    k_agg<0><<<(N + 15) / 16, 256, 0, stream>>>(Th, row_ptr, csr, dinv, b1, H, nullptr, nullptr, N);

    // ---- layer 2 + fused final projection ----
    k_gemm_mfma<_Float16><<<1024, 256, 0, stream>>>(H, W2, dinv, Th, N, nRB);
    k_agg<1><<<(N + 15) / 16, 256, 0, stream>>>(Th, row_ptr, csr, dinv, b2, out, Wl, bl, N);
}